// Round 1
// baseline (104.347 us; speedup 1.0000x reference)
//
#include <hip/hip_runtime.h>
#include <math.h>

#define K_SIGN 1000.0f
#define EPSILON 5.0f

// tanhf(K*d - EPS) is EXACTLY +-1.0f for |K*d - EPS| >= 12.
#define D_HI ((EPSILON + 12.0f) / K_SIGN)   // d > D_HI  -> +1.0f exactly
#define D_LO ((EPSILON - 12.0f) / K_SIGN)   // d < D_LO  -> -1.0f exactly

#define NBE 256   // edge-atomic blocks in k_main

// Only equal-p pairs can be in-band; p_j<p_i contributes exactly +1, p_j>p_i
// exactly -1. S is only ever consumed as a difference within an equal-p group,
// so it is recomputed in k_out from the global histogram T (bit-identical f32
// ops) instead of being materialized -- the old k_merge kernel is gone, and the
// 64-way privatized Hpriv (2 MB write + 2 MB read + 64-deep fan-in) is replaced
// by direct device-scope atomics into the 32 KB T array (~512 cache lines,
// uniform spread -> low per-line contention).
//
// ws layout: C double @0 (16B) | T i32[n] | PFX i32[n+4] | order i32[n]

__global__ void __launch_bounds__(256) k_zero(int4* __restrict__ T4, int n4) {
    int i = blockIdx.x * 256 + threadIdx.x;
    if (i < n4) T4[i] = make_int4(0, 0, 0, 0);
}

// blocks 0..NBE-1: T[dst] += (int)p[src] via global atomics (segment max
// cancels: mx + log(se) = log(T)).
// block NBE (aux): p-histogram fused with dot (one pass), exclusive scan ->
// PFX, then counting-sort scatter -> order, all block-local (runs concurrently
// with the edge blocks; touches neither T nor the edge list).
__global__ void __launch_bounds__(256) k_main(
        const int* __restrict__ src, const int* __restrict__ dst,
        const float* __restrict__ p, const float* __restrict__ x,
        int* __restrict__ T, double* __restrict__ C,
        int* __restrict__ PFX, int* __restrict__ order, int e, int n) {
    int tid = threadIdx.x;
    int b = blockIdx.x;

    if (b < NBE) {
        for (int t = b * 256 + tid; t < e; t += NBE * 256)
            atomicAdd(&T[dst[t]], (int)p[src[t]]);
        return;
    }

    // aux block
    __shared__ int buf[8192];                 // n == 8192
    __shared__ int csum[256];
    __shared__ double dred[4];
    int4* b4 = (int4*)buf;
    for (int i = tid; i < n / 4; i += 256) b4[i] = make_int4(0, 0, 0, 0);
    __syncthreads();

    double acc = 0.0;
    for (int i = tid; i < n; i += 256) {
        float pv = p[i];
        atomicAdd(&buf[(int)pv - 1], 1);
        acc += (double)x[i] * (double)pv;     // same order as prior rounds -> C identical
    }
    for (int off = 32; off > 0; off >>= 1)
        acc += __shfl_down(acc, off, 64);
    if ((tid & 63) == 0) dred[tid >> 6] = acc;
    __syncthreads();                          // hist atomics + dred complete
    if (tid == 0) *C = dred[0] + dred[1] + dred[2] + dred[3];

    // chunked exclusive scan of the 8192-bin histogram
    int cw = n / 256;                         // 32 bins/thread
    int base = tid * cw;
    int s = 0;
    for (int k = 0; k < cw; ++k) s += buf[base + k];
    csum[tid] = s;
    __syncthreads();
    for (int off = 1; off < 256; off <<= 1) {
        int v = (tid >= off) ? csum[tid - off] : 0;
        __syncthreads();
        csum[tid] += v;
        __syncthreads();
    }
    int run = (tid == 0) ? 0 : csum[tid - 1];
    for (int k = 0; k < cw; ++k) {
        int h = buf[base + k];
        PFX[base + k] = run;
        buf[base + k] = run;                  // buf becomes the scatter cursor
        run += h;
    }
    if (tid == 0) PFX[n] = n;                 // sentinel
    __syncthreads();

    // counting-sort scatter, block-local (replaces k_merge's global scatter)
    for (int i = tid; i < n; i += 256) {
        int r = atomicAdd(&buf[(int)p[i] - 1], 1);
        order[r] = i;
    }
}

// out[i] = #{p_j<p_i} - #{p_j>p_i} + sum over the equal-p group of the exact
// f32 band predicate / tanhf (self-pair d=0 -> tanhf(-EPS) included).
// S[j] is recomputed from T[j] with the same f32 expression the old k_merge
// used, so d = si - sj is bit-identical to the previous version.
__global__ void __launch_bounds__(64) k_out(
        const int* __restrict__ T, const float* __restrict__ p,
        const double* __restrict__ C, const int* __restrict__ PFX,
        const int* __restrict__ order, float* __restrict__ out,
        int n, float log_n) {
    int i = blockIdx.x * 64 + threadIdx.x;
    if (i >= n) return;
    float pv = p[i];
    int pi = (int)pv;
    float Cf = (float)(*C);
    int base = PFX[pi - 1];                   // #{p_j < p_i}, also group start
    int g = PFX[pi] - base;                   // group size (>=1: contains i)
    int ti = T[i] + pi;                       // + self-loop term p[i]
    float si = (logf((float)ti) + pv * log_n) + Cf;
    float accf = (float)(base - (n - base - g));
    for (int k = 0; k < g; ++k) {
        int j = order[base + k];
        int tj = T[j] + pi;                   // p[j] == p[i] exactly (same bin)
        float sj = (logf((float)tj) + pv * log_n) + Cf;
        float d = si - sj;
        if (d > D_HI) accf += 1.0f;
        else if (d < D_LO) accf -= 1.0f;
        else accf += tanhf(fmaf(K_SIGN, d, -EPSILON));
    }
    out[i] = accf;
}

extern "C" void kernel_launch(void* const* d_in, const int* in_sizes, int n_in,
                              void* d_out, int out_size, void* d_ws, size_t ws_size,
                              hipStream_t stream) {
    const int* edge_index = (const int*)d_in[0];
    const float* p = (const float*)d_in[1];
    const float* x = (const float*)d_in[2];
    float* out = (float*)d_out;

    int e = in_sizes[0] / 2;
    int n = in_sizes[1];
    const int* src = edge_index;       // row 0
    const int* dst = edge_index + e;   // row 1

    double* C = (double*)d_ws;
    int* T = (int*)((char*)d_ws + 16);
    int* PFX = T + n;                         // n+1 ints, padded
    int* order = PFX + (n + 4);

    float log_n = logf((float)n);

    k_zero<<<(n / 4 + 255) / 256, 256, 0, stream>>>((int4*)T, n / 4);
    k_main<<<NBE + 1, 256, 0, stream>>>(src, dst, p, x, T, C, PFX, order, e, n);
    k_out<<<(n + 63) / 64, 64, 0, stream>>>(T, p, C, PFX, order, out, n, log_n);
}

// Round 2
// 95.575 us; speedup vs baseline: 1.0918x; 1.0918x over previous
//
#include <hip/hip_runtime.h>
#include <math.h>

#define K_SIGN 1000.0f
#define EPSILON 5.0f

// tanhf(K*d - EPS) is EXACTLY +-1.0f for |K*d - EPS| >= 12.
#define D_HI ((EPSILON + 12.0f) / K_SIGN)   // d > D_HI  -> +1.0f exactly
#define D_LO ((EPSILON - 12.0f) / K_SIGN)   // d < D_LO  -> -1.0f exactly

#define NB_HIST 64

// Lesson from round 1: device-scope atomics write through the fabric on
// gfx950 (WRITE_SIZE showed 32 B/atomic to HBM) -> 262k edge atomics cost
// ~48 us. LDS-privatized histograms (round 0) are ~10x faster; this round
// keeps them and instead parallelizes the 64-way fan-in merge (round 0 ran
// it 64-deep serial on only 32 CUs).
//
// ws layout: C double @0 (16B) | S f32[N] | PFX i32[N+4] | order i32[N]
//            | Hpriv i32[NB_HIST][N]

// blocks 0..NB-1: privatized LDS histogram T[d] += (int)p[src]  (segment max
// cancels: mx + log(se) = log(T)).
// block NB (aux): p-histogram fused with dot (one pass), exclusive scan ->
// PFX, counting-sort scatter -> order via LDS cursor (no global atomics).
__global__ void __launch_bounds__(256) k_hist(
        const int* __restrict__ src, const int* __restrict__ dst,
        const float* __restrict__ p, const float* __restrict__ x,
        int* __restrict__ Hpriv, double* __restrict__ C,
        int* __restrict__ PFX, int* __restrict__ order, int e, int n) {
    __shared__ int buf[8192];                 // n == 8192 (union of roles)
    __shared__ int csum[256];
    __shared__ double dred[4];
    int tid = threadIdx.x;
    int b = blockIdx.x;

    int4* b4 = (int4*)buf;
    for (int i = tid; i < n / 4; i += 256) b4[i] = make_int4(0, 0, 0, 0);
    __syncthreads();

    if (b < NB_HIST) {
        int per = (e + NB_HIST - 1) / NB_HIST;
        int t0 = b * per;
        int t1 = min(t0 + per, e);
        for (int t = t0 + tid; t < t1; t += 256)
            atomicAdd(&buf[dst[t]], (int)p[src[t]]);
        __syncthreads();
        int4* o4 = (int4*)(Hpriv + b * n);
        for (int i = tid; i < n / 4; i += 256) o4[i] = b4[i];
        return;
    }

    // aux block: p-histogram + dot in ONE pass over the nodes
    double acc = 0.0;
    for (int i = tid; i < n; i += 256) {
        float pv = p[i];
        atomicAdd(&buf[(int)pv - 1], 1);
        acc += (double)x[i] * (double)pv;     // same order as prior rounds -> C identical
    }
    for (int off = 32; off > 0; off >>= 1)
        acc += __shfl_down(acc, off, 64);
    if ((tid & 63) == 0) dred[tid >> 6] = acc;
    __syncthreads();                          // hist atomics + dred complete
    if (tid == 0) *C = dred[0] + dred[1] + dred[2] + dred[3];

    // chunked exclusive scan of the 8192-bin histogram
    int cw = n / 256;                         // 32 bins/thread
    int base = tid * cw;
    int s = 0;
    for (int k = 0; k < cw; ++k) s += buf[base + k];
    csum[tid] = s;
    __syncthreads();
    for (int off = 1; off < 256; off <<= 1) {
        int v = (tid >= off) ? csum[tid - off] : 0;
        __syncthreads();
        csum[tid] += v;
        __syncthreads();
    }
    int run = (tid == 0) ? 0 : csum[tid - 1];
    for (int k = 0; k < cw; ++k) {
        int h = buf[base + k];
        PFX[base + k] = run;
        buf[base + k] = run;                  // buf becomes the scatter cursor
        run += h;
    }
    if (tid == 0) PFX[n] = n;                 // sentinel
    __syncthreads();

    // counting-sort scatter, block-local (order within a group arbitrary)
    for (int i = tid; i < n; i += 256) {
        int r = atomicAdd(&buf[(int)p[i] - 1], 1);
        order[r] = i;
    }
}

// 4 threads per node: each sums 16 of the 64 partial histograms, LDS combine
// (integer adds -> T bit-identical to any summation order), then
// S[i] = log(T) + p*log_n + C.  128 blocks -> 4x the CU coverage and 1/4 the
// serial load depth of the round-0 merge.
__global__ void __launch_bounds__(256) k_merge(
        const int* __restrict__ Hpriv, const float* __restrict__ p,
        const double* __restrict__ C, float* __restrict__ S,
        int n, float log_n) {
    __shared__ int part[4][64];
    int q = threadIdx.x >> 6;                 // 0..3: which 16 histograms
    int l = threadIdx.x & 63;
    int i = blockIdx.x * 64 + l;
    int s = 0;
#pragma unroll
    for (int b = q * 16; b < q * 16 + 16; ++b) s += Hpriv[b * n + i];
    part[q][l] = s;
    __syncthreads();
    if (q == 0) {
        float pv = p[i];
        int t = (int)pv + part[0][l] + part[1][l] + part[2][l] + part[3][l];
        S[i] = (logf((float)t) + pv * log_n) + (float)(*C);
    }
}

// out[i] = #{p_j<p_i} - #{p_j>p_i} + sum over the equal-p group of the exact
// f32 band predicate / tanhf (self-pair d=0 -> tanhf(-EPS) included).
__global__ void __launch_bounds__(64) k_out(const float* __restrict__ S,
                                            const float* __restrict__ p,
                                            const int* __restrict__ PFX,
                                            const int* __restrict__ order,
                                            float* __restrict__ out, int n) {
    int i = blockIdx.x * 64 + threadIdx.x;
    if (i >= n) return;
    int pi = (int)p[i];
    int base = PFX[pi - 1];                   // #{p_j < p_i}, also group start
    int g = PFX[pi] - base;                   // group size (>=1: contains i)
    float si = S[i];
    float acc = (float)(base - (n - base - g));
    for (int k = 0; k < g; ++k) {
        int j = order[base + k];
        float d = si - S[j];
        if (d > D_HI) acc += 1.0f;
        else if (d < D_LO) acc -= 1.0f;
        else acc += tanhf(fmaf(K_SIGN, d, -EPSILON));
    }
    out[i] = acc;
}

extern "C" void kernel_launch(void* const* d_in, const int* in_sizes, int n_in,
                              void* d_out, int out_size, void* d_ws, size_t ws_size,
                              hipStream_t stream) {
    const int* edge_index = (const int*)d_in[0];
    const float* p = (const float*)d_in[1];
    const float* x = (const float*)d_in[2];
    float* out = (float*)d_out;

    int e = in_sizes[0] / 2;
    int n = in_sizes[1];
    const int* src = edge_index;       // row 0
    const int* dst = edge_index + e;   // row 1

    double* C = (double*)d_ws;
    float* S = (float*)((char*)d_ws + 16);
    int* PFX = (int*)(S + n);                 // n+1 ints, padded
    int* order = PFX + (n + 4);
    int* Hpriv = order + n;

    float log_n = logf((float)n);

    k_hist<<<NB_HIST + 1, 256, 0, stream>>>(src, dst, p, x, Hpriv, C,
                                            PFX, order, e, n);
    k_merge<<<n / 64, 256, 0, stream>>>(Hpriv, p, C, S, n, log_n);
    k_out<<<n / 64, 64, 0, stream>>>(S, p, PFX, order, out, n);
}